// Round 7
// baseline (290.993 us; speedup 1.0000x reference)
//
#include <hip/hip_runtime.h>
#include <hip/hip_bf16.h>
#include <stdint.h>

// Pipeline:
//   1. prep: cvt query/key_value fp32->bf16 + transpose+cvt Wq/Wk/Wv/Wo (1 kernel)
//   2. gemm_qkv (one launch, z=0/1/2):
//        z0: Q = (qb @ WqT + bq)*0.125*log2e -> bf16 [8192,1024] row-major
//        z1: K -> Kf FRAGMENT-ORDER layout: [bh][kt(kv/32)][chunk(d/8)][r(kv%32)][8]
//        z2: V -> Vf FRAGMENT-ORDER layout: [bh][wt(kv/64)][ch][d(64)][8]
//            (ch content kv-permuted per swap23 so P^T reg order matches)
//   3. attn: NO LDS, NO BARRIERS. K/V fragments read as perfectly-coalesced
//      1KB global b128 loads, register ping-pong prefetch one 32-kv step ahead
//      -> compiler emits fine-grained vmcnt(N) (AITER-style pipelining).
//      S^T = K.Q^T via 32x32x16; P^T regs feed PV 32x32x16 directly.
//      64 q/wave (two q-sets) so each K/V load feeds 2 MFMAs. No-max softmax.
//   4. gemm_o: out = X @ WoT + bo -> fp32

typedef unsigned short u16;
typedef __attribute__((ext_vector_type(2))) float f32x2;
typedef __attribute__((ext_vector_type(4))) short bf16x4;
typedef __attribute__((ext_vector_type(8))) short bf16x8;
typedef __attribute__((ext_vector_type(4))) float f32x4;
typedef __attribute__((ext_vector_type(16))) float f32x16;

__device__ __forceinline__ u16 f2bf(float x) {
  union { float f; uint32_t u; } c; c.f = x;
  uint32_t r = c.u + 0x7fffu + ((c.u >> 16) & 1u);
  return (u16)(r >> 16);
}

__device__ __forceinline__ uint32_t pkbf(float a, float b) {
#if __has_builtin(__builtin_amdgcn_cvt_pk_bf16_f32)
  typedef __attribute__((ext_vector_type(2))) __bf16 bf2;
  bf2 r = __builtin_amdgcn_cvt_pk_bf16_f32(a, b);
  return __builtin_bit_cast(uint32_t, r);
#else
  return (uint32_t)f2bf(a) | ((uint32_t)f2bf(b) << 16);
#endif
}

__device__ __forceinline__ void gld16(const void* g, void* l) {
  __builtin_amdgcn_global_load_lds(
      (const __attribute__((address_space(1))) void*)g,
      (__attribute__((address_space(3))) void*)l, 16, 0, 0);
}

// ---------------- fused prep: cvt x2 + transpose x4 in one launch ----------
__device__ __forceinline__ void cvt_body(const float* __restrict__ in,
                                         u16* __restrict__ out, int blk) {
  int i = (blk * 256 + threadIdx.x) * 8;
  float4 a = *(const float4*)(in + i);
  float4 b = *(const float4*)(in + i + 4);
  union { u16 u[8]; uint4 v; } o;
  o.u[0] = f2bf(a.x); o.u[1] = f2bf(a.y); o.u[2] = f2bf(a.z); o.u[3] = f2bf(a.w);
  o.u[4] = f2bf(b.x); o.u[5] = f2bf(b.y); o.u[6] = f2bf(b.z); o.u[7] = f2bf(b.w);
  *(uint4*)(out + i) = o.v;
}

__device__ __forceinline__ void transpose_body(const float* __restrict__ in,
                                               u16* __restrict__ out,
                                               int R, int C, int bx, int by) {
  __shared__ float tile[64][65];
  int c0 = bx * 64, r0 = by * 64;
  #pragma unroll
  for (int it = 0; it < 16; it++) {
    int idx = threadIdx.x + it * 256;
    int lr = idx >> 6, lc = idx & 63;
    tile[lr][lc] = in[(size_t)(r0 + lr) * C + c0 + lc];
  }
  __syncthreads();
  #pragma unroll
  for (int it = 0; it < 16; it++) {
    int idx = threadIdx.x + it * 256;
    int lc = idx >> 6, lr = idx & 63;
    out[(size_t)(c0 + lc) * R + r0 + lr] = f2bf(tile[lr][lc]);
  }
}

__global__ void prep_kernel(const float* __restrict__ query,
                            const float* __restrict__ key_value,
                            const float* __restrict__ Wq, const float* __restrict__ Wk,
                            const float* __restrict__ Wv, const float* __restrict__ Wo,
                            u16* qb, u16* kvb, u16* WqT, u16* WkT, u16* WvT, u16* WoT) {
  int blk = blockIdx.x;
  if (blk < 4096) { cvt_body(query, qb, blk); return; }
  if (blk < 7168) { cvt_body(key_value, kvb, blk - 4096); return; }
  if (blk < 7424) { int lo = blk - 7168; transpose_body(Wq, WqT, 1024, 1024, lo & 15, lo >> 4); return; }
  if (blk < 7616) { int lo = blk - 7424; transpose_body(Wk, WkT, 768, 1024, lo & 15, lo >> 4); return; }
  if (blk < 7808) { int lo = blk - 7616; transpose_body(Wv, WvT, 768, 1024, lo & 15, lo >> 4); return; }
  { int lo = blk - 7808; transpose_body(Wo, WoT, 1024, 1024, lo & 15, lo >> 4); return; }
}

// ---------------- shared GEMM K-loop (128x128 tile, BK=64) -----------------
template<bool SWAP>
__device__ __forceinline__ void gemm_kloop(const u16* __restrict__ A,
                                           const u16* __restrict__ BT,
                                           int K, char* smem, f32x4 (&acc)[4][4],
                                           int m0, int n0, int tid) {
  const u16* ap[4]; const u16* bp[4]; int ldA[4], ldB[4];
  #pragma unroll
  for (int it2 = 0; it2 < 4; it2++) {
    int s = it2 * 256 + tid;
    int row = s >> 3, cl = (s & 7) ^ (row & 7);
    ap[it2] = A + (size_t)(m0 + row) * K + cl * 8;
    bp[it2] = BT + (size_t)(n0 + row) * K + cl * 8;
    ldA[it2] = s * 16;
    ldB[it2] = 16384 + s * 16;
  }
  const int w = tid >> 6, l = tid & 63;
  const int lm = l & 15, lq = l >> 4;
  const int wr = w >> 1, wc = w & 1;
  int abase[4], bbase[4];
  #pragma unroll
  for (int i = 0; i < 4; i++) {
    int m = wr * 64 + i * 16 + lm;
    abase[i] = m * 128 + ((lq ^ (m & 7)) << 4);
    int n = wc * 64 + i * 16 + lm;
    bbase[i] = 16384 + n * 128 + ((lq ^ (n & 7)) << 4);
  }
  for (int k0 = 0; k0 < K; k0 += 64) {
    #pragma unroll
    for (int it2 = 0; it2 < 4; it2++) {
      gld16(ap[it2], smem + ldA[it2]);
      gld16(bp[it2], smem + ldB[it2]);
      ap[it2] += 64; bp[it2] += 64;
    }
    __syncthreads();
    #pragma unroll
    for (int kk = 0; kk < 2; kk++) {
      bf16x8 af[4], bf[4];
      #pragma unroll
      for (int i = 0; i < 4; i++)
        af[i] = *(const bf16x8*)(smem + (abase[i] ^ (kk << 6)));
      #pragma unroll
      for (int j = 0; j < 4; j++)
        bf[j] = *(const bf16x8*)(smem + (bbase[j] ^ (kk << 6)));
      #pragma unroll
      for (int i = 0; i < 4; i++)
        #pragma unroll
        for (int j = 0; j < 4; j++) {
          if (SWAP)
            acc[i][j] = __builtin_amdgcn_mfma_f32_16x16x32_bf16(bf[j], af[i], acc[i][j], 0, 0, 0);
          else
            acc[i][j] = __builtin_amdgcn_mfma_f32_16x16x32_bf16(af[i], bf[j], acc[i][j], 0, 0, 0);
        }
    }
    __syncthreads();
  }
}

// ---------------- fused QKV projection GEMM (z = 0:Q, 1:K, 2:V) ------------
__global__ __launch_bounds__(256, 3)
void gemm_qkv(const u16* __restrict__ qb, const u16* __restrict__ kvb,
              const u16* __restrict__ WqT, const u16* __restrict__ WkT,
              const u16* __restrict__ WvT,
              const float* __restrict__ bq, const float* __restrict__ bk,
              const float* __restrict__ bv,
              u16* __restrict__ Qb, u16* __restrict__ Kf, u16* __restrict__ Vf,
              float qscale) {
  extern __shared__ __align__(16) char smem[];
  const int tid = threadIdx.x;
  const int w = tid >> 6, l = tid & 63;
  const int lm = l & 15, lq = l >> 4;
  const int m0 = blockIdx.y * 128, n0 = blockIdx.x * 128;
  const int wr = w >> 1, wc = w & 1;
  const int z = blockIdx.z;
  f32x4 acc[4][4] = {};

  u16* etile = (u16*)(smem + w * 9216);
  const int xr = l >> 3, cc = (l & 7) ^ xr;

  if (z < 2) {
    const u16* A = (z == 0) ? qb : kvb;
    const u16* BT = (z == 0) ? WqT : WkT;
    const float* bias = (z == 0) ? bq : bk;
    const float scale = (z == 0) ? qscale : 1.0f;
    const int K = (z == 0) ? 1024 : 768;
    gemm_kloop<true>(A, BT, K, smem, acc, m0, n0, tid);
    // etile[m-local(rows)][n-local(cols)], stride 72
    #pragma unroll
    for (int j = 0; j < 4; j++) {
      float4 b4 = *(const float4*)&bias[n0 + wc * 64 + j * 16 + lq * 4];
      #pragma unroll
      for (int i = 0; i < 4; i++) {
        uint2 pkd;
        pkd.x = pkbf((acc[i][j][0] + b4.x) * scale, (acc[i][j][1] + b4.y) * scale);
        pkd.y = pkbf((acc[i][j][2] + b4.z) * scale, (acc[i][j][3] + b4.w) * scale);
        *(uint2*)&etile[(i * 16 + lm) * 72 + j * 16 + lq * 4] = pkd;
      }
    }
    if (z == 0) {
      u16* gbase = Qb + (size_t)(m0 + wr * 64) * 1024 + n0 + wc * 64;
      #pragma unroll
      for (int co = 0; co < 8; co++) {
        int ml = co * 8 + xr;
        uint4 d = *(const uint4*)&etile[ml * 72 + cc * 8];
        *(uint4*)&gbase[(size_t)ml * 1024 + cc * 8] = d;
      }
    } else {
      // K fragment layout: [bh][kt=kv/32][chunk=d/8][r=kv%32][8]
      const int kvg = m0 + wr * 64;                       // 64-row chunk, b-aligned
      const int bh_ = ((kvg >> 11) << 4) + ((n0 + wc * 64) >> 6);
      u16* gK = Kf + (size_t)bh_ * 131072 + (size_t)((kvg & 2047) >> 5) * 2048;
      #pragma unroll
      for (int co = 0; co < 8; co++) {
        int ml = co * 8 + xr;
        uint4 d = *(const uint4*)&etile[ml * 72 + cc * 8];
        *(uint4*)&gK[(ml >> 5) * 2048 + cc * 256 + (ml & 31) * 8] = d;
      }
    }
  } else {
    gemm_kloop<false>(kvb, WvT, 768, smem, acc, m0, n0, tid);
    // etile[n-local(d)][m-local(kv)], stride 72
    #pragma unroll
    for (int j = 0; j < 4; j++) {
      float bi = bv[n0 + wc * 64 + j * 16 + lm];
      #pragma unroll
      for (int i = 0; i < 4; i++) {
        uint2 pkd;
        pkd.x = pkbf(acc[i][j][0] + bi, acc[i][j][1] + bi);
        pkd.y = pkbf(acc[i][j][2] + bi, acc[i][j][3] + bi);
        *(uint2*)&etile[(j * 16 + lm) * 72 + i * 16 + lq * 4] = pkd;
      }
    }
    // V fragment layout: [bh][wt=kv/64][ch][d(64)][8]; ch content swap23-permuted
    const int bh_ = ((m0 >> 11) << 4) + ((n0 + wc * 64) >> 6);
    const int wt = ((m0 & 2047) + wr * 64) >> 6;
    u16* gV = Vf + (size_t)bh_ * 131072 + (size_t)wt * 4096;
    const int kvA = (cc >> 1) * 16 + (cc & 1) * 4;        // swap23(cc*8)
    #pragma unroll
    for (int co = 0; co < 8; co++) {
      int dl = co * 8 + xr;
      uint2 dA = *(const uint2*)&etile[dl * 72 + kvA];
      uint2 dB = *(const uint2*)&etile[dl * 72 + kvA + 8];
      uint4 d = {dA.x, dA.y, dB.x, dB.y};
      *(uint4*)&gV[cc * 512 + dl * 8] = d;
    }
  }
}

// ---------------- O-projection GEMM (fp32 out) -----------------------------
__global__ __launch_bounds__(256, 3)
void gemm_o(const u16* __restrict__ A, const u16* __restrict__ BT,
            const float* __restrict__ bias, float* __restrict__ Cout) {
  __shared__ __align__(16) char smem[32768];
  const int tid = threadIdx.x;
  const int w = tid >> 6, l = tid & 63;
  const int lm = l & 15, lq = l >> 4;
  const int m0 = blockIdx.y * 128, n0 = blockIdx.x * 128;
  const int wr = w >> 1, wc = w & 1;
  f32x4 acc[4][4] = {};
  gemm_kloop<false>(A, BT, 1024, smem, acc, m0, n0, tid);
  #pragma unroll
  for (int j = 0; j < 4; j++) {
    int gn = n0 + wc * 64 + j * 16 + lm;
    float bi = bias[gn];
    #pragma unroll
    for (int i = 0; i < 4; i++) {
      int gm = m0 + wr * 64 + i * 16 + lq * 4;
      #pragma unroll
      for (int r = 0; r < 4; r++)
        Cout[(size_t)(gm + r) * 1024 + gn] = acc[i][j][r] + bi;
    }
  }
}

// ---------------- flash attention: LDS-free, barrier-free ------------------
// One 32-kv step; register ping-pong prefetch (kc/vc compute, kn/vn loading).
template<bool PREF>
__device__ __forceinline__ void attn_step(
    const u16*& kp, const u16*& vp,
    const bf16x8 (&kc)[4], const bf16x8 (&vc)[4],
    bf16x8 (&kn)[4], bf16x8 (&vn)[4],
    const bf16x8 (&qfA)[4], const bf16x8 (&qfB)[4],
    f32x16 (&xA)[2], f32x16 (&xB)[2], f32x2& lsA, f32x2& lsB) {
  if (PREF) {
    #pragma unroll
    for (int t = 0; t < 4; t++) kn[t] = *(const bf16x8*)(kp + t * 512);
    #pragma unroll
    for (int c2 = 0; c2 < 2; c2++)
      #pragma unroll
      for (int dt = 0; dt < 2; dt++)
        vn[c2 * 2 + dt] = *(const bf16x8*)(vp + c2 * 1024 + dt * 256);
    kp += 2048; vp += 2048;
  }
  const f32x16 KZ = {};
  f32x16 stA = __builtin_amdgcn_mfma_f32_32x32x16_bf16(kc[0], qfA[0], KZ, 0, 0, 0);
  f32x16 stB = __builtin_amdgcn_mfma_f32_32x32x16_bf16(kc[0], qfB[0], KZ, 0, 0, 0);
  #pragma unroll
  for (int t = 1; t < 4; t++) {
    stA = __builtin_amdgcn_mfma_f32_32x32x16_bf16(kc[t], qfA[t], stA, 0, 0, 0);
    stB = __builtin_amdgcn_mfma_f32_32x32x16_bf16(kc[t], qfB[t], stB, 0, 0, 0);
  }
  uint32_t pkA[8], pkB[8];
  #pragma unroll
  for (int u = 0; u < 4; u++) {
    float a0 = __builtin_amdgcn_exp2f(stA[4 * u + 0]);
    float a1 = __builtin_amdgcn_exp2f(stA[4 * u + 1]);
    float a2 = __builtin_amdgcn_exp2f(stA[4 * u + 2]);
    float a3 = __builtin_amdgcn_exp2f(stA[4 * u + 3]);
    lsA += (f32x2){a0 + a2, a1 + a3};
    pkA[2 * u] = pkbf(a0, a1); pkA[2 * u + 1] = pkbf(a2, a3);
    float b0 = __builtin_amdgcn_exp2f(stB[4 * u + 0]);
    float b1 = __builtin_amdgcn_exp2f(stB[4 * u + 1]);
    float b2 = __builtin_amdgcn_exp2f(stB[4 * u + 2]);
    float b3 = __builtin_amdgcn_exp2f(stB[4 * u + 3]);
    lsB += (f32x2){b0 + b2, b1 + b3};
    pkB[2 * u] = pkbf(b0, b1); pkB[2 * u + 1] = pkbf(b2, b3);
  }
  #pragma unroll
  for (int c2 = 0; c2 < 2; c2++) {
    union { uint32_t d[4]; bf16x8 v; } pfA, pfB;
    #pragma unroll
    for (int dd = 0; dd < 4; dd++) { pfA.d[dd] = pkA[4 * c2 + dd]; pfB.d[dd] = pkB[4 * c2 + dd]; }
    #pragma unroll
    for (int dt = 0; dt < 2; dt++) {
      xA[dt] = __builtin_amdgcn_mfma_f32_32x32x16_bf16(vc[c2 * 2 + dt], pfA.v, xA[dt], 0, 0, 0);
      xB[dt] = __builtin_amdgcn_mfma_f32_32x32x16_bf16(vc[c2 * 2 + dt], pfB.v, xB[dt], 0, 0, 0);
    }
  }
}

// Q: bf16 [B*2048,1024]. Kf/Vf: fragment-order (see gemm_qkv). X: [B*2048,1024].
__global__ __launch_bounds__(256, 2)
void attn_kernel(const u16* __restrict__ Q, const u16* __restrict__ Kf,
                 const u16* __restrict__ Vf, u16* __restrict__ X) {
  const int tid = threadIdx.x, w = tid >> 6, l = tid & 63;
  const int l31 = l & 31, h5 = l >> 5;
  const int bh = blockIdx.x, b = bh >> 4, h = bh & 15;  // x=bh: 8 q-blocks/bh on one XCD
  const int q0 = blockIdx.y * 256 + w * 64;

  bf16x8 qfA[4], qfB[4];
  {
    const u16* qp = Q + ((size_t)(b * 2048 + q0 + l31)) * 1024 + h * 64 + h5 * 8;
    #pragma unroll
    for (int t = 0; t < 4; t++) qfA[t] = *(const bf16x8*)(qp + t * 16);
    qp += (size_t)32 * 1024;
    #pragma unroll
    for (int t = 0; t < 4; t++) qfB[t] = *(const bf16x8*)(qp + t * 16);
  }

  // per-lane fragment pointers (coalesced: wave covers 1KB contiguous per load)
  const u16* kp = Kf + (size_t)bh * 131072 + h5 * 256 + l31 * 8;
  const u16* vp = Vf + (size_t)bh * 131072 + h5 * 512 + l31 * 8;

  f32x16 xA[2] = {}, xB[2] = {};
  f32x2 lsA = {0.f, 0.f}, lsB = {0.f, 0.f};

  bf16x8 KA[4], VA[4], KB[4], VB[4];
  #pragma unroll
  for (int t = 0; t < 4; t++) KA[t] = *(const bf16x8*)(kp + t * 512);
  #pragma unroll
  for (int c2 = 0; c2 < 2; c2++)
    #pragma unroll
    for (int dt = 0; dt < 2; dt++)
      VA[c2 * 2 + dt] = *(const bf16x8*)(vp + c2 * 1024 + dt * 256);
  kp += 2048; vp += 2048;

  for (int s2 = 0; s2 < 31; s2++) {
    attn_step<true>(kp, vp, KA, VA, KB, VB, qfA, qfB, xA, xB, lsA, lsB);
    attn_step<true>(kp, vp, KB, VB, KA, VA, qfA, qfB, xA, xB, lsA, lsB);
  }
  attn_step<true>(kp, vp, KA, VA, KB, VB, qfA, qfB, xA, xB, lsA, lsB);
  attn_step<false>(kp, vp, KB, VB, KA, VA, qfA, qfB, xA, xB, lsA, lsB);

  {
    float lsum = lsA[0] + lsA[1];
    const float inv = 1.0f / (lsum + __shfl_xor(lsum, 32));
    u16* xp = X + ((size_t)(b * 2048 + q0 + l31)) * 1024 + h * 64;
    #pragma unroll
    for (int dt = 0; dt < 2; dt++)
      #pragma unroll
      for (int g = 0; g < 4; g++) {
        const int d0 = dt * 32 + g * 8 + h5 * 4;
        uint2 o;
        o.x = pkbf(xA[dt][4 * g + 0] * inv, xA[dt][4 * g + 1] * inv);
        o.y = pkbf(xA[dt][4 * g + 2] * inv, xA[dt][4 * g + 3] * inv);
        *(uint2*)(xp + d0) = o;
      }
  }
  {
    float lsum = lsB[0] + lsB[1];
    const float inv = 1.0f / (lsum + __shfl_xor(lsum, 32));
    u16* xp = X + ((size_t)(b * 2048 + q0 + 32 + l31)) * 1024 + h * 64;
    #pragma unroll
    for (int dt = 0; dt < 2; dt++)
      #pragma unroll
      for (int g = 0; g < 4; g++) {
        const int d0 = dt * 32 + g * 8 + h5 * 4;
        uint2 o;
        o.x = pkbf(xB[dt][4 * g + 0] * inv, xB[dt][4 * g + 1] * inv);
        o.y = pkbf(xB[dt][4 * g + 2] * inv, xB[dt][4 * g + 3] * inv);
        *(uint2*)(xp + d0) = o;
      }
  }
}

// ---------------------------------------------------------------------------
extern "C" void kernel_launch(void* const* d_in, const int* in_sizes, int n_in,
                              void* d_out, int out_size, void* d_ws, size_t ws_size,
                              hipStream_t stream) {
  const float* query     = (const float*)d_in[0];
  const float* key_value = (const float*)d_in[1];
  const float* Wq = (const float*)d_in[2];
  const float* bq = (const float*)d_in[3];
  const float* Wk = (const float*)d_in[4];
  const float* bk = (const float*)d_in[5];
  const float* Wv = (const float*)d_in[6];
  const float* bv = (const float*)d_in[7];
  const float* Wo = (const float*)d_in[8];
  const float* bo = (const float*)d_in[9];
  float* out = (float*)d_out;

  char* ws = (char*)d_ws;
  size_t off = 0;
  auto alloc = [&](size_t bytes) -> void* {
    void* p = ws + off; off += (bytes + 255) & ~(size_t)255; return p;
  };
  u16* qb  = (u16*)alloc((size_t)8192 * 1024 * 2);
  u16* kvb = (u16*)alloc((size_t)8192 * 768 * 2);
  u16* WqT = (u16*)alloc((size_t)1024 * 1024 * 2);
  u16* WkT = (u16*)alloc((size_t)1024 * 768 * 2);
  u16* WvT = (u16*)alloc((size_t)1024 * 768 * 2);
  u16* WoT = (u16*)alloc((size_t)1024 * 1024 * 2);
  u16* Qb  = (u16*)alloc((size_t)8192 * 1024 * 2);
  u16* Kf  = (u16*)alloc((size_t)8192 * 1024 * 2);
  u16* Vf  = (u16*)alloc((size_t)8192 * 1024 * 2);
  u16* Xb  = (u16*)alloc((size_t)8192 * 1024 * 2);

  prep_kernel<<<8064, 256, 0, stream>>>(query, key_value, Wq, Wk, Wv, Wo,
                                        qb, kvb, WqT, WkT, WvT, WoT);

  const float qscale = 0.125f * 1.4426950408889634f;  // D^-1/2 * log2(e)
  gemm_qkv<<<dim3(8, 64, 3), 256, 36864, stream>>>(qb, kvb, WqT, WkT, WvT,
                                                   bq, bk, bv, Qb, Kf, Vf, qscale);

  attn_kernel<<<dim3(64, 8), 256, 0, stream>>>(Qb, Kf, Vf, Xb);

  gemm_o<<<dim3(8, 64), 256, 0, stream>>>(Xb, WoT, bo, out);
}